// Round 3
// baseline (508.274 us; speedup 1.0000x reference)
//
#include <hip/hip_runtime.h>

// GraphPool: out[i] = max(A[i], max_j A[adj_d[i - d*PER_DEG][j]]) where d = i / PER_DEG.
// Layout: 440000 rows x 128 fp32 features. Degrees 0..10, 40000 rows each, contiguous.
#define N_ATOMS 440000
#define F_DIM   128
#define PER_DEG 40000
#define MAX_DEG 10

// LLC blocking (R2, kept): feature dim in 4 column slices of 32 floats (128 B/row).
#define PHASES          4
#define LANES_PER_ROW   8                       // 8 x f32x4 = 32 floats = 128 B slice
#define ROWS_PER_BLOCK  32                      // 256 threads / 8 lanes per row
#define BLOCKS_PER_PHASE (N_ATOMS / ROWS_PER_BLOCK)   // 13750 (exact: 40000 % 32 == 0)

// Native vector type so __builtin_nontemporal_store accepts it (HIP float4 is a class).
typedef float f32x4 __attribute__((ext_vector_type(4)));

// 10 adjacency pointers passed by value as a kernel argument (no device alloc needed).
struct AdjPtrs { const int* p[MAX_DEG]; };

// R3 lever: memory-level parallelism. Previous versions compiled to VGPR_Count=12,
// which only allows ~2 outstanding f32x4 gathers per thread -> gather chain serializes
// into back-to-back latencies (same 2 KB/wave in flight in R0/R1/R2, same 3.7 TB/s).
// __launch_bounds__(256, 6) caps VGPRs at ~85 (6 waves/SIMD), enough to hold all 10
// gather results in flight; sched_barrier(0) pins all issues before any consume.
__global__ __launch_bounds__(256, 6) void graphpool_kernel(
    const f32x4* __restrict__ A,   // atom_features viewed as f32x4, row stride 32
    AdjPtrs adj,
    f32x4* __restrict__ out)
{
    const int phase = blockIdx.x / BLOCKS_PER_PHASE;          // 0..3 (compile-time magic-mul)
    const int rblk  = blockIdx.x - phase * BLOCKS_PER_PHASE;
    const int row   = rblk * ROWS_PER_BLOCK + (threadIdx.x >> 3);
    const int slot  = (phase << 3) + (threadIdx.x & 7);       // f32x4 slot 0..31
    // 40000 % 32 == 0 -> degree is uniform across the whole block.
    const int d     = row / PER_DEG;                          // 0..10
    const int local = row - d * PER_DEG;

    const size_t rbase = (size_t)row * (F_DIM / 4);
    f32x4 v = A[rbase + slot];                                // self features (one 128B line)

    if (d > 0) {
        const int* idx = adj.p[d - 1] + (size_t)local * d;

        // Load all indices first (contiguous ints, broadcast across the 8 lanes).
        int nbrs[MAX_DEG];
        #pragma unroll
        for (int j = 0; j < MAX_DEG; ++j) {
            if (j < d) nbrs[j] = idx[j];
        }

        // Issue ALL gathers into distinct registers -- up to 10 x 128 B in flight
        // per 8-lane group. Fully unrolled, compile-time indices only (no scratch).
        f32x4 rv[MAX_DEG];
        #pragma unroll
        for (int j = 0; j < MAX_DEG; ++j) {
            if (j < d) rv[j] = A[(size_t)nbrs[j] * (F_DIM / 4) + slot];
        }

        // Pin program order: no fmax (or its s_waitcnt) may be hoisted above the
        // issue loop, so all gathers are outstanding before the first consume.
        __builtin_amdgcn_sched_barrier(0);

        #pragma unroll
        for (int j = 0; j < MAX_DEG; ++j) {
            if (j < d) {
                v.x = fmaxf(v.x, rv[j].x);
                v.y = fmaxf(v.y, rv[j].y);
                v.z = fmaxf(v.z, rv[j].z);
                v.w = fmaxf(v.w, rv[j].w);
            }
        }
    }

    // nt store measured neutral at MALL level (R1); kept as harmless L1/L2 hint.
    __builtin_nontemporal_store(v, &out[rbase + slot]);
}

extern "C" void kernel_launch(void* const* d_in, const int* in_sizes, int n_in,
                              void* d_out, int out_size, void* d_ws, size_t ws_size,
                              hipStream_t stream) {
    // d_in[0] = atom_features (float32, 440000*128)
    // d_in[1] = deg_slice (int32, 11x2) -- structure is fixed by setup_inputs; not needed
    // d_in[2..11] = adj1..adj10 (int32, 40000*d each)
    const f32x4* A = (const f32x4*)d_in[0];
    AdjPtrs adj;
    for (int i = 0; i < MAX_DEG; ++i) adj.p[i] = (const int*)d_in[2 + i];
    f32x4* out = (f32x4*)d_out;

    const int blocks = BLOCKS_PER_PHASE * PHASES;   // 55000
    graphpool_kernel<<<blocks, 256, 0, stream>>>(A, adj, out);
}